// Round 8
// baseline (590.996 us; speedup 1.0000x reference)
//
#include <hip/hip_runtime.h>
#include <math.h>

#define Bb 8
#define Nn 2048
#define Mm 2048
#define Cc 512

typedef __attribute__((ext_vector_type(8))) _Float16 hfrag;  // 8 f16 = 4 VGPRs
typedef __attribute__((ext_vector_type(4))) float f4;        // MFMA acc
typedef __attribute__((ext_vector_type(4))) _Float16 h4;

__device__ __forceinline__ void gld16(const void* g, void* l) {
    __builtin_amdgcn_global_load_lds(
        (const __attribute__((address_space(1))) void*)g,
        (__attribute__((address_space(3))) void*)l, 16, 0, 0);
}

// counted vmcnt wait + scheduler fence (rule #18) -- used by gemm_mfma
template<int N> __device__ __forceinline__ void wait_vmcnt() {
    if constexpr (N == 0)      asm volatile("s_waitcnt vmcnt(0)" ::: "memory");
    else if constexpr (N == 3) asm volatile("s_waitcnt vmcnt(3)" ::: "memory");
    else if constexpr (N == 4) asm volatile("s_waitcnt vmcnt(4)" ::: "memory");
    __builtin_amdgcn_sched_barrier(0);
}

// ---------------------------------------------------------------------------
// attn_fused v2: score + masked-softmax + PV + gate, NO operand staging.
// r6 post-mortem: v1 was occupancy-bound (1 wave/SIMD, 141KB LDS, 256 VGPR)
// with ~216 exposed barriers. v2 removes ALL operand LDS: MFMA fragments
// are loaded directly from global (per-lane 16B = row lcol, k = quad*8 --
// exactly the A/B fragment layout). enc (2MB) + vT (2MB) are L2-resident
// per XCD (batch->XCD swizzle, 64 blocks share them); Q tile is 32KB and
// L1/L2-hot across the 8 m-tile re-reads. LDS holds only the P tile (16KB,
// XOR-swizzled exactly as r6, enumerated) + reduce arrays -> 17KB.
// Block: 256 thr / 4 waves, n-tile 32, grid 512 = 2 blocks/CU, 2 waves/SIMD.
// Barriers: 3 per m-tile (24 total vs r6's ~216); S and PV inner loops are
// barrier-free pure dataflow the compiler can software-pipeline.
// Per mt (m-tile of 256):
//   S:  sa[4][2] += enc-frags x Q-frags, k=C (16 steps, direct loads)
//   A:  mask-mult (f4) + wave-local per-n max -> MXS; S1
//   B:  m_new = max(mrun, 4 waves) [mrun init 0 = zeros participate];
//       al = exp(m_old-m_new); P = exp(s-m_new), s==0 -> 0 (exact r6
//       semantics); P -> PL swizzled; l-partials -> LSS; S2
//   C:  lrun = lrun*al + sum(LSS); o *= al (lane-local: shared n<->lane map)
//   PV: o[8][2] += vT-frags x P-frags, k=m256 (8 steps, V direct, P from
//       PL); S4 (PL reusable)
// Finalize: g = dec_h * (1 + tanh(o/lrun)).
// ---------------------------------------------------------------------------
__global__ __launch_bounds__(256, 2) void attn_fused(
    const _Float16* __restrict__ Eg,   // enc_h [8][2048][512]
    const _Float16* __restrict__ Qg,   // dec_h [8][2048][512]
    const _Float16* __restrict__ Vg,   // vT    [8][512][2048]
    const float*    __restrict__ Mg,   // mask  [8][2048][2048] fp32
    _Float16* __restrict__ Gg)         // g out [8][2048][512]
{
    __shared__ _Float16 PL[32 * 256];      // P tile, 16 KB, XOR-swizzled
    __shared__ float MXS[4][32];
    __shared__ float LSS[4][32];

    const int id = blockIdx.x;
    const int bz = id & 7;                 // batch -> XCD
    const int n0 = (id >> 3) * 32;

    const _Float16* E0 = Eg + (size_t)bz * ((size_t)Mm * Cc);
    const _Float16* Q0 = Qg + (size_t)bz * ((size_t)Nn * Cc) + (size_t)n0 * Cc;
    const _Float16* V0 = Vg + (size_t)bz * ((size_t)Cc * Mm);
    const float*    M0 = Mg + (size_t)bz * ((size_t)Nn * Mm);

    const int tid = threadIdx.x;
    const int wv = tid >> 6, ln = tid & 63;
    const int lcol = ln & 15, quad = ln >> 4;
    char* PLb = (char*)PL;

    // per-lane fragment base pointers (k-offset quad*8 folded in)
    const _Float16* Eln = E0 + (size_t)(wv * 64 + lcol) * Cc + quad * 8;
    const _Float16* Qln = Q0 + (size_t)lcol * Cc + quad * 8;
    const _Float16* Vln = V0 + (size_t)(wv * 128 + lcol) * Mm + quad * 8;

    f4 o[8][2];                            // c = wv*128+i*16+quad*4+r, n = j*16+lcol
    const f4 z4 = {0.f, 0.f, 0.f, 0.f};
    #pragma unroll
    for (int i = 0; i < 8; ++i)
        #pragma unroll
        for (int j = 0; j < 2; ++j) o[i][j] = z4;
    float mrun[2] = {0.f, 0.f};            // init 0 = masked zeros participate
    float lrun[2] = {0.f, 0.f};

    for (int mt = 0; mt < 8; ++mt) {
        const int m0 = mt * 256;

        // ---- S-phase: sa += enc x Q (direct loads, no barriers) --------
        f4 sa[4][2];
        #pragma unroll
        for (int i = 0; i < 4; ++i)
            #pragma unroll
            for (int j = 0; j < 2; ++j) sa[i][j] = z4;

        {
            const _Float16* Ei0 = Eln + (size_t)m0 * Cc;
            #pragma unroll
            for (int t = 0; t < 16; ++t) {
                hfrag af[4], bf[2];
                #pragma unroll
                for (int i = 0; i < 4; ++i)
                    af[i] = *(const hfrag*)(Ei0 + (size_t)(i * 16) * Cc + t * 32);
                #pragma unroll
                for (int j = 0; j < 2; ++j)
                    bf[j] = *(const hfrag*)(Qln + (size_t)(j * 16) * Cc + t * 32);
                #pragma unroll
                for (int i = 0; i < 4; ++i)
                    #pragma unroll
                    for (int j = 0; j < 2; ++j)
                        sa[i][j] = __builtin_amdgcn_mfma_f32_16x16x32_f16(af[i], bf[j], sa[i][j], 0, 0, 0);
            }
        }

        // ---- A-phase: mask + wave-local max ----------------------------
        const float* Mkb = M0 + (size_t)(n0 + lcol) * Mm + m0 + wv * 64 + quad * 4;
        #pragma unroll
        for (int j = 0; j < 2; ++j) {
            f4 mk[4];
            #pragma unroll
            for (int i = 0; i < 4; ++i)
                mk[i] = *(const f4*)(Mkb + (size_t)j * 16 * Mm + i * 16);
            #pragma unroll
            for (int i = 0; i < 4; ++i)
                #pragma unroll
                for (int r = 0; r < 4; ++r) sa[i][j][r] *= mk[i][r];
            float mx = 0.f;
            #pragma unroll
            for (int i = 0; i < 4; ++i)
                #pragma unroll
                for (int r = 0; r < 4; ++r) mx = fmaxf(mx, sa[i][j][r]);
            mx = fmaxf(mx, __shfl_xor(mx, 16, 64));
            mx = fmaxf(mx, __shfl_xor(mx, 32, 64));
            if (quad == 0) MXS[wv][j * 16 + lcol] = mx;
        }
        __syncthreads();                                   // S1

        // ---- B-phase: m_new/alpha, P -> PL, l-partials -----------------
        float al[2], mnew[2];
        #pragma unroll
        for (int j = 0; j < 2; ++j) {
            const int n = j * 16 + lcol;
            float mm = mrun[j];
            mm = fmaxf(mm, MXS[0][n]); mm = fmaxf(mm, MXS[1][n]);
            mm = fmaxf(mm, MXS[2][n]); mm = fmaxf(mm, MXS[3][n]);
            al[j] = __expf(mrun[j] - mm);
            mrun[j] = mm; mnew[j] = mm;
        }
        #pragma unroll
        for (int j = 0; j < 2; ++j) {
            const int n = j * 16 + lcol;
            float lp = 0.f;
            #pragma unroll
            for (int i = 0; i < 4; ++i) {
                h4 pv;
                #pragma unroll
                for (int r = 0; r < 4; ++r) {
                    const float s = sa[i][j][r];
                    const float e = __expf(s - mnew[j]);
                    lp += e;
                    pv[r] = (s == 0.f) ? (_Float16)0.f : (_Float16)e;
                }
                *(h4*)(PLb + n * 512 +
                       (((wv << 7) + (i << 5) + (quad << 3)) ^ ((n & 7) << 4))) = pv;
            }
            lp += __shfl_xor(lp, 16, 64);
            lp += __shfl_xor(lp, 32, 64);
            if (quad == 0) LSS[wv][n] = lp;
        }
        __syncthreads();                                   // S2

        // ---- C-phase: l_run update + o rescale -------------------------
        #pragma unroll
        for (int j = 0; j < 2; ++j) {
            const int n = j * 16 + lcol;
            const float ls = LSS[0][n] + LSS[1][n] + LSS[2][n] + LSS[3][n];
            lrun[j] = lrun[j] * al[j] + ls;
            #pragma unroll
            for (int i = 0; i < 8; ++i)
                #pragma unroll
                for (int r = 0; r < 4; ++r) o[i][j][r] *= al[j];
        }

        // ---- PV-phase: o += vT x P (V direct, P from PL, no barriers) --
        #pragma unroll
        for (int t = 0; t < 8; ++t) {
            hfrag va[8], pb[2];
            #pragma unroll
            for (int i = 0; i < 8; ++i)
                va[i] = *(const hfrag*)(Vln + (size_t)(i * 16) * Mm + m0 + t * 32);
            #pragma unroll
            for (int j = 0; j < 2; ++j) {
                const int n = j * 16 + lcol;
                pb[j] = *(const hfrag*)(PLb + n * 512 +
                        (((t << 6) + (quad << 4)) ^ ((n & 7) << 4)));
            }
            #pragma unroll
            for (int i = 0; i < 8; ++i)
                #pragma unroll
                for (int j = 0; j < 2; ++j)
                    o[i][j] = __builtin_amdgcn_mfma_f32_16x16x32_f16(va[i], pb[j], o[i][j], 0, 0, 0);
        }
        __syncthreads();                                   // S4: PL reusable
    }

    // ---- finalize: g = dec_h * (1 + tanh(o/l)) -------------------------
    const _Float16* Db = Qg + (size_t)bz * ((size_t)Nn * Cc);
    _Float16* Gb = Gg + (size_t)bz * ((size_t)Nn * Cc);
    #pragma unroll
    for (int j = 0; j < 2; ++j) {
        const int n = n0 + j * 16 + lcol;
        const float inv = 1.f / lrun[j];
        #pragma unroll
        for (int i = 0; i < 8; ++i) {
            const int c0 = wv * 128 + i * 16 + quad * 4;
            const h4 dv = *(const h4*)(Db + (size_t)n * Cc + c0);
            h4 gv;
            #pragma unroll
            for (int r = 0; r < 4; ++r) {
                const float a = o[i][j][r] * inv;
                const float th = 1.f - 2.f / (__expf(2.f * a) + 1.f);
                gv[r] = (_Float16)((float)dv[r] * (1.f + th));
            }
            *(h4*)(Gb + (size_t)n * Cc + c0) = gv;
        }
    }
}

// ---------------------------------------------------------------------------
// MFMA GEMM (f16 in, fp32 acc), 128xBN tile, BK=32, ring-of-3 LDS buffers,
// counted vmcnt + raw s_barrier (r3 structure, verified). EPI 1/3/4 only.
// ---------------------------------------------------------------------------
template<int EPI, int BN, int SWZ>
__global__ __launch_bounds__(256) void gemm_mfma(
    const _Float16* __restrict__ Ah, long sA, int lda,
    const _Float16* __restrict__ Bh, long sB, int ldb,
    const float* __restrict__ aux, long sAux, int ldaux,     // f32 bias
    void* __restrict__ Cout, long sC, int ldc, int K, int GX)
{
    constexpr int NI  = (BN == 128) ? 4 : 2;
    constexpr int ASL = 512;
    constexpr int BSL = BN * 4;
    constexpr int NQ  = (ASL + BSL) / 256;

    __shared__ _Float16 As[3][128 * 32];
    __shared__ _Float16 Bs[3][BN * 32];

    int bx, by, bz;
    if (SWZ == 1) {
        const int id = blockIdx.x;
        bz = id & 7; bx = (id >> 3) % GX; by = (id >> 3) / GX;
    } else if (SWZ == 2) {
        const int id = blockIdx.x;
        bz = 0; bx = (id >> 3) % GX; by = (id & 7) + 8 * ((id >> 3) / GX);
    } else {
        bx = blockIdx.x; by = blockIdx.y; bz = 0;
    }

    const _Float16* A0 = Ah + (size_t)bz * sA;
    const _Float16* B0 = Bh + (size_t)bz * sB;

    const int tid  = threadIdx.x;
    const int wv   = tid >> 6;
    const int ln   = tid & 63;
    const int wx   = (BN == 128) ? (wv & 1) : 0;
    const int wy   = (BN == 128) ? (wv >> 1) : wv;
    const int lcol = ln & 15, quad = ln >> 4;
    const int row0w = wy * (NI * 16);
    const int col0w = wx * 64;

    const int rowBase = by * 128;
    const int colBase = bx * BN;
    const int soff = (quad ^ ((lcol >> 1) & 3)) * 8;

    f4 acc[NI][4];
    const f4 z4 = {0.f, 0.f, 0.f, 0.f};
    #pragma unroll
    for (int i = 0; i < NI; ++i)
        #pragma unroll
        for (int j = 0; j < 4; ++j) acc[i][j] = z4;

    auto STAGE = [&](int k0, int p) {
        #pragma unroll
        for (int q = 0; q < NQ; ++q) {
            const int c = q * 256 + wv * 64 + ln;
            if (c < ASL) {
                const int r = c >> 2;
                const int g = (c & 3) ^ ((c >> 3) & 3);
                gld16(A0 + (size_t)(rowBase + r) * lda + k0 + g * 8, &As[p][c * 8]);
            } else {
                const int cb = c - ASL;
                const int r  = cb >> 2;
                const int g  = (cb & 3) ^ ((cb >> 3) & 3);
                gld16(B0 + (size_t)(colBase + r) * ldb + k0 + g * 8, &Bs[p][cb * 8]);
            }
        }
    };

    const int NT = K >> 5;
    STAGE(0, 0);
    STAGE(32, 1);
    wait_vmcnt<NQ>();
    __builtin_amdgcn_s_barrier();

    int p = 0, pn2 = 2;
    for (int t = 0; t < NT; ++t) {
        if (t + 2 < NT) STAGE((t + 2) * 32, pn2);

        hfrag af[NI], bf_[4];
        #pragma unroll
        for (int i = 0; i < NI; ++i)
            af[i]  = *(const hfrag*)&As[p][(row0w + i * 16 + lcol) * 32 + soff];
        #pragma unroll
        for (int j = 0; j < 4; ++j)
            bf_[j] = *(const hfrag*)&Bs[p][(col0w + j * 16 + lcol) * 32 + soff];

        #pragma unroll
        for (int i = 0; i < NI; ++i)
            #pragma unroll
            for (int j = 0; j < 4; ++j)
                acc[i][j] = __builtin_amdgcn_mfma_f32_16x16x32_f16(af[i], bf_[j], acc[i][j], 0, 0, 0);

        if (t + 1 < NT) {
            if (t + 2 < NT) wait_vmcnt<NQ>();
            else            wait_vmcnt<0>();
            __builtin_amdgcn_s_barrier();
        }
        p   = (p   == 2) ? 0 : p + 1;
        pn2 = (pn2 == 2) ? 0 : pn2 + 1;
    }

    const int crow0 = rowBase + row0w + quad * 4;
    const int ccol0 = colBase + col0w + lcol;

    if (EPI == 1) {            // v^T: vT[b][c][m] = acc + bias[c], h4
        _Float16* C = (_Float16*)Cout;
        #pragma unroll
        for (int j = 0; j < 4; ++j) {
            const int col = ccol0 + j * 16;
            const float bi = aux[col];
            #pragma unroll
            for (int i = 0; i < NI; ++i) {
                const int rowb = crow0 + i * 16;
                const int bb = rowb >> 11, ml = rowb & 2047;
                h4 st;
                #pragma unroll
                for (int r = 0; r < 4; ++r) st[r] = (_Float16)(acc[i][j][r] + bi);
                *(h4*)(C + (size_t)bb * ((size_t)Cc * Mm) + (size_t)col * Mm + ml) = st;
            }
        }
    } else if (EPI == 3) {     // fc1: h[n][c2] = relu(acc + b1[c2]), h4
        _Float16* C = (_Float16*)Cout;
        #pragma unroll
        for (int i = 0; i < NI; ++i) {
            const int c0 = crow0 + i * 16;
            const f4 bi = *(const f4*)(aux + c0);
            #pragma unroll
            for (int j = 0; j < 4; ++j) {
                const int n = ccol0 + j * 16;
                h4 hv;
                #pragma unroll
                for (int r = 0; r < 4; ++r)
                    hv[r] = (_Float16)fmaxf(acc[i][j][r] + bi[r], 0.f);
                *(h4*)(C + (size_t)n * ldc + c0) = hv;
            }
        }
    } else {                   // fc2: out[n][c3] = acc + b2[c3], f4 stores
        float* C = (float*)Cout;
        #pragma unroll
        for (int i = 0; i < NI; ++i) {
            const int c0 = crow0 + i * 16;
            const f4 bi = *(const f4*)(aux + c0);
            #pragma unroll
            for (int j = 0; j < 4; ++j) {
                const int n = ccol0 + j * 16;
                f4 ov;
                #pragma unroll
                for (int r = 0; r < 4; ++r) ov[r] = acc[i][j][r] + bi[r];
                *(f4*)(C + (size_t)n * ldc + c0) = ov;
            }
        }
    }
}

// fp32 -> f16, vectorized x4. grid*256*4 == element count.
__global__ __launch_bounds__(256) void sconv(const float* __restrict__ x,
                                             _Float16* __restrict__ o)
{
    const size_t i = (size_t)blockIdx.x * 256 + threadIdx.x;
    f4 v = ((const f4*)x)[i];
    h4 hh;
    #pragma unroll
    for (int k = 0; k < 4; ++k) hh[k] = (_Float16)v[k];
    ((h4*)o)[i] = hh;
}

// W [512,512] fp32 -> Wt [512,512] f16 transposed (Wt[n][k] = W[k][n]).
__global__ __launch_bounds__(256) void wconv(const float* s0, const float* s1, const float* s2,
                                             _Float16* d0, _Float16* d1, _Float16* d2)
{
    const float* Sm = blockIdx.z == 0 ? s0 : blockIdx.z == 1 ? s1 : s2;
    _Float16* D = blockIdx.z == 0 ? d0 : blockIdx.z == 1 ? d1 : d2;
    __shared__ float t[32][33];
    const int x = threadIdx.x & 31, y = threadIdx.x >> 5;
    const int gx = blockIdx.x * 32, gy = blockIdx.y * 32;
    #pragma unroll
    for (int yy = y; yy < 32; yy += 8)
        t[yy][x] = Sm[(size_t)(gy + yy) * 512 + gx + x];
    __syncthreads();
    #pragma unroll
    for (int yy = y; yy < 32; yy += 8)
        D[(size_t)(gx + yy) * 512 + gy + x] = (_Float16)t[x][yy];
}

// ---------------------------------------------------------------------------
// ws layout:
//   dec_h[0x4600000, 0x5600000)  f16 [bn][c]
//   Wvt/W1t/W2t [0x5600000, +3*512KB)
//   vT   [0x5800000, 0x6800000)  f16 [b][c][m]
//   g    [0x6800000, 0x7800000)  f16 [bn][c]
//   h    [0x7800000, 0x8800000)  f16 [bn][c2]
//   enc_h in d_out (dead before fc2 writes).
// ---------------------------------------------------------------------------
extern "C" void kernel_launch(void* const* d_in, const int* in_sizes, int n_in,
                              void* d_out, int out_size, void* d_ws, size_t ws_size,
                              hipStream_t stream)
{
    const float* dec   = (const float*)d_in[0];
    const float* enc   = (const float*)d_in[1];
    const float* trans = (const float*)d_in[2];
    const float* Wv = (const float*)d_in[3];
    const float* bv = (const float*)d_in[4];
    const float* W1 = (const float*)d_in[5];
    const float* b1 = (const float*)d_in[6];
    const float* W2 = (const float*)d_in[7];
    const float* b2 = (const float*)d_in[8];

    char* ws = (char*)d_ws;
    _Float16* dec_h = (_Float16*)(ws + 0x4600000);
    _Float16* Wvt   = (_Float16*)(ws + 0x5600000);
    _Float16* W1t   = Wvt + 262144;
    _Float16* W2t   = Wvt + 524288;
    _Float16* vT    = (_Float16*)(ws + 0x5800000);
    _Float16* g     = (_Float16*)(ws + 0x6800000);
    _Float16* h     = (_Float16*)(ws + 0x7800000);
    _Float16* enc_h = (_Float16*)d_out;

    sconv<<<dim3(8192), 256, 0, stream>>>(dec, dec_h);
    sconv<<<dim3(8192), 256, 0, stream>>>(enc, enc_h);
    wconv<<<dim3(16, 16, 3), 256, 0, stream>>>(Wv, W1, W2, Wvt, W1t, W2t);

    // v^T = (enc @ Wv + bv)^T  [b][c][m]   [SWZ2, GX=8]
    gemm_mfma<1, 64, 2><<<dim3(1024), 256, 0, stream>>>(
        enc_h, 0, 512, Wvt, 0, 512, bv, 0, 0,
        vT, 0, 0, 512, 8);

    // fused: score + masked-softmax + PV + gate -> g  (n-tile 32, 2 blk/CU)
    attn_fused<<<dim3(512), 256, 0, stream>>>(enc_h, dec_h, vT, trans, g);

    // h[n][c2] = relu(g @ W1 + b1):  A=W1^T (rows=c2), B=g (cols=n)
    gemm_mfma<3, 64, 0><<<dim3(256, 4), 256, 0, stream>>>(
        W1t, 0, 512, g, 0, 512, b1, 0, 0,
        h, 0, 512, 512, 0);

    // out[n][c3] = h @ W2 + b2:  A=W2^T (rows=c3), B=h (cols=n), fp32
    gemm_mfma<4, 64, 0><<<dim3(256, 4), 256, 0, stream>>>(
        W2t, 0, 512, h, 0, 512, b2, 0, 0,
        d_out, 0, 512, 512, 0);
}

// Round 9
// 507.759 us; speedup vs baseline: 1.1639x; 1.1639x over previous
//
#include <hip/hip_runtime.h>
#include <math.h>

#define Bb 8
#define Nn 2048
#define Mm 2048
#define Cc 512

typedef __attribute__((ext_vector_type(8))) _Float16 hfrag;  // 8 f16 = 4 VGPRs
typedef __attribute__((ext_vector_type(4))) float f4;        // MFMA acc
typedef __attribute__((ext_vector_type(4))) _Float16 h4;

__device__ __forceinline__ void gld16(const void* g, void* l) {
    __builtin_amdgcn_global_load_lds(
        (const __attribute__((address_space(1))) void*)g,
        (__attribute__((address_space(3))) void*)l, 16, 0, 0);
}

// counted vmcnt wait + scheduler fence (rule #18) -- used by gemm_mfma
template<int N> __device__ __forceinline__ void wait_vmcnt() {
    if constexpr (N == 0)      asm volatile("s_waitcnt vmcnt(0)" ::: "memory");
    else if constexpr (N == 3) asm volatile("s_waitcnt vmcnt(3)" ::: "memory");
    else if constexpr (N == 4) asm volatile("s_waitcnt vmcnt(4)" ::: "memory");
    __builtin_amdgcn_sched_barrier(0);
}

// ---------------------------------------------------------------------------
// Fragment-blocked layouts (r8 post-mortem: direct 16B frag loads from
// row-major scatter 16 cache lines/instr -> request-rate bound, MfmaUtil 8%).
// Blocked [rows/16][k/32][16][32] f16 makes a wave's MFMA fragment load
// (lane addr = lcol*32 + quad*8) ONE contiguous 1KB transaction.
//   EB enc [8][m/16][c/32][16][32]: e(m,c) at (m>>4)*8192+(c>>5)*512+(m&15)*32+(c&31)
//   DB dec [8][n/16][c/32][16][32]: same with n
//   VB v   [8][c/16][m/32][16][32]: (c>>4)*32768+(m>>5)*512+(c&15)*32+(m&31)
// EB/DB written by sconv2 (dual-layout); VB written by EPI1 epilogue.
// ---------------------------------------------------------------------------

// fp32 -> f16: linear copy (optional) + fragment-blocked copy.
__global__ __launch_bounds__(256) void sconv2(const float* __restrict__ x,
                                              _Float16* __restrict__ lin,
                                              _Float16* __restrict__ blk)
{
    const size_t i = (size_t)blockIdx.x * 256 + threadIdx.x;
    f4 v = ((const f4*)x)[i];
    h4 hh;
    #pragma unroll
    for (int k = 0; k < 4; ++k) hh[k] = (_Float16)v[k];
    if (lin) ((h4*)lin)[i] = hh;
    const size_t e0 = i * 4;
    const size_t b = e0 >> 20;                 // 2048*512 = 1M elems/batch
    const int    w = (int)(e0 & 1048575);
    const int    r = w >> 9, c = w & 511;      // c multiple of 4
    *(h4*)(blk + b * 1048576 +
           ((r >> 4) * 8192 + (c >> 5) * 512 + (r & 15) * 32 + (c & 31))) = hh;
}

// ---------------------------------------------------------------------------
// attn_fused v3: score + masked-softmax + PV + gate. Operands direct from
// global in BLOCKED layout (coalesced 1KB/instr); LDS = P tile only (16KB,
// XOR-swizzled, silicon-proven r6). launch_bounds(256,2): VGPR cap 256 ->
// no spill (r8: 128-cap spilled ~78MB scratch). Grid 512 = 2 blocks/CU.
// Per mt (m-tile 256): S (16 steps, 6 loads/8 MFMA, barrier-free) ->
// mask+max -> online-softmax P->PL -> rescale -> PV (8 steps, barrier-free).
// 3 barriers per mt. Softmax: mrun init 0 (masked zeros participate);
// P zeroed where s==0 (exact reference semantics, proven r6).
// ---------------------------------------------------------------------------
__global__ __launch_bounds__(256, 2) void attn_fused(
    const _Float16* __restrict__ EBg,  // enc blocked
    const _Float16* __restrict__ DBg,  // dec blocked
    const _Float16* __restrict__ VBg,  // v blocked
    const float*    __restrict__ Mg,   // mask [8][2048][2048] fp32
    _Float16* __restrict__ Gg)         // g out [8][2048][512] linear
{
    __shared__ _Float16 PL[32 * 256];      // P tile, 16 KB, XOR-swizzled
    __shared__ float MXS[4][32];
    __shared__ float LSS[4][32];

    const int id = blockIdx.x;
    const int bz = id & 7;                 // batch -> XCD
    const int n0 = (id >> 3) * 32;

    const _Float16* E0 = EBg + (size_t)bz * ((size_t)Mm * Cc);
    const _Float16* D0 = DBg + (size_t)bz * ((size_t)Nn * Cc);
    const _Float16* V0 = VBg + (size_t)bz * ((size_t)Cc * Mm);
    const float*    M0 = Mg  + (size_t)bz * ((size_t)Nn * Mm);

    const int tid = threadIdx.x;
    const int wv = tid >> 6, ln = tid & 63;
    const int lcol = ln & 15, quad = ln >> 4;
    const int eoff = lcol * 32 + quad * 8;     // lane offset within 1KB frag
    char* PLb = (char*)PL;

    // fragment base pointers
    const _Float16* Qf = D0 + (n0 >> 4) * 8192 + eoff;       // + j*8192 + t*512
    const _Float16* Ef = E0 + (wv * 4) * 8192 + eoff;        // + ((m0>>4)+i)*8192 + t*512
    const _Float16* Vf = V0 + (wv * 8) * 32768 + eoff;       // + i*32768 + ((m0>>5)+t)*512

    f4 o[8][2];                            // c = wv*128+i*16+quad*4+r, n = j*16+lcol
    const f4 z4 = {0.f, 0.f, 0.f, 0.f};
    #pragma unroll
    for (int i = 0; i < 8; ++i)
        #pragma unroll
        for (int j = 0; j < 2; ++j) o[i][j] = z4;
    float mrun[2] = {0.f, 0.f};            // init 0 = masked zeros participate
    float lrun[2] = {0.f, 0.f};

    for (int mt = 0; mt < 8; ++mt) {
        const int m0 = mt * 256;

        // ---- S-phase: sa += enc x Q (coalesced direct loads) -----------
        f4 sa[4][2];
        #pragma unroll
        for (int i = 0; i < 4; ++i)
            #pragma unroll
            for (int j = 0; j < 2; ++j) sa[i][j] = z4;

        #pragma unroll
        for (int t = 0; t < 16; ++t) {
            hfrag af[4], bf[2];
            #pragma unroll
            for (int i = 0; i < 4; ++i)
                af[i] = *(const hfrag*)(Ef + (size_t)((m0 >> 4) + i) * 8192 + t * 512);
            #pragma unroll
            for (int j = 0; j < 2; ++j)
                bf[j] = *(const hfrag*)(Qf + (size_t)j * 8192 + t * 512);
            #pragma unroll
            for (int i = 0; i < 4; ++i)
                #pragma unroll
                for (int j = 0; j < 2; ++j)
                    sa[i][j] = __builtin_amdgcn_mfma_f32_16x16x32_f16(af[i], bf[j], sa[i][j], 0, 0, 0);
        }

        // ---- A-phase: mask + wave-local max ----------------------------
        const float* Mkb = M0 + (size_t)(n0 + lcol) * Mm + m0 + wv * 64 + quad * 4;
        #pragma unroll
        for (int j = 0; j < 2; ++j) {
            f4 mk[4];
            #pragma unroll
            for (int i = 0; i < 4; ++i)
                mk[i] = *(const f4*)(Mkb + (size_t)j * 16 * Mm + i * 16);
            #pragma unroll
            for (int i = 0; i < 4; ++i)
                #pragma unroll
                for (int r = 0; r < 4; ++r) sa[i][j][r] *= mk[i][r];
            float mx = 0.f;
            #pragma unroll
            for (int i = 0; i < 4; ++i)
                #pragma unroll
                for (int r = 0; r < 4; ++r) mx = fmaxf(mx, sa[i][j][r]);
            mx = fmaxf(mx, __shfl_xor(mx, 16, 64));
            mx = fmaxf(mx, __shfl_xor(mx, 32, 64));
            if (quad == 0) MXS[wv][j * 16 + lcol] = mx;
        }
        __syncthreads();                                   // S1

        // ---- B-phase: m_new/alpha, P -> PL, l-partials -----------------
        float al[2], mnew[2];
        #pragma unroll
        for (int j = 0; j < 2; ++j) {
            const int n = j * 16 + lcol;
            float mm = mrun[j];
            mm = fmaxf(mm, MXS[0][n]); mm = fmaxf(mm, MXS[1][n]);
            mm = fmaxf(mm, MXS[2][n]); mm = fmaxf(mm, MXS[3][n]);
            al[j] = __expf(mrun[j] - mm);
            mrun[j] = mm; mnew[j] = mm;
        }
        #pragma unroll
        for (int j = 0; j < 2; ++j) {
            const int n = j * 16 + lcol;
            float lp = 0.f;
            #pragma unroll
            for (int i = 0; i < 4; ++i) {
                h4 pv;
                #pragma unroll
                for (int r = 0; r < 4; ++r) {
                    const float s = sa[i][j][r];
                    const float e = __expf(s - mnew[j]);
                    lp += e;
                    pv[r] = (s == 0.f) ? (_Float16)0.f : (_Float16)e;
                }
                *(h4*)(PLb + n * 512 +
                       (((wv << 7) + (i << 5) + (quad << 3)) ^ ((n & 7) << 4))) = pv;
            }
            lp += __shfl_xor(lp, 16, 64);
            lp += __shfl_xor(lp, 32, 64);
            if (quad == 0) LSS[wv][n] = lp;
        }
        __syncthreads();                                   // S2

        // ---- C-phase: l_run update + o rescale -------------------------
        #pragma unroll
        for (int j = 0; j < 2; ++j) {
            const int n = j * 16 + lcol;
            const float ls = LSS[0][n] + LSS[1][n] + LSS[2][n] + LSS[3][n];
            lrun[j] = lrun[j] * al[j] + ls;
            #pragma unroll
            for (int i = 0; i < 8; ++i)
                #pragma unroll
                for (int r = 0; r < 4; ++r) o[i][j][r] *= al[j];
        }

        // ---- PV-phase: o += v x P (coalesced V, P from PL) -------------
        #pragma unroll
        for (int t = 0; t < 8; ++t) {
            hfrag va[8], pb[2];
            #pragma unroll
            for (int i = 0; i < 8; ++i)
                va[i] = *(const hfrag*)(Vf + (size_t)i * 32768 + (size_t)((m0 >> 5) + t) * 512);
            #pragma unroll
            for (int j = 0; j < 2; ++j) {
                const int n = j * 16 + lcol;
                pb[j] = *(const hfrag*)(PLb + n * 512 +
                        (((t << 6) + (quad << 4)) ^ ((n & 7) << 4)));
            }
            #pragma unroll
            for (int i = 0; i < 8; ++i)
                #pragma unroll
                for (int j = 0; j < 2; ++j)
                    o[i][j] = __builtin_amdgcn_mfma_f32_16x16x32_f16(va[i], pb[j], o[i][j], 0, 0, 0);
        }
        __syncthreads();                                   // S3: PL reusable
    }

    // ---- finalize: g = dec * (1 + tanh(o/l)), dec read from DB blocked --
    _Float16* Gb = Gg + (size_t)bz * ((size_t)Nn * Cc);
    #pragma unroll
    for (int j = 0; j < 2; ++j) {
        const int n = n0 + j * 16 + lcol;
        const float inv = 1.f / lrun[j];
        const _Float16* Dn = D0 + (size_t)(n >> 4) * 8192 + (n & 15) * 32;
        #pragma unroll
        for (int i = 0; i < 8; ++i) {
            const int c0 = wv * 128 + i * 16 + quad * 4;
            const h4 dv = *(const h4*)(Dn + (c0 >> 5) * 512 + (c0 & 31));
            h4 gv;
            #pragma unroll
            for (int r = 0; r < 4; ++r) {
                const float a = o[i][j][r] * inv;
                const float th = 1.f - 2.f / (__expf(2.f * a) + 1.f);
                gv[r] = (_Float16)((float)dv[r] * (1.f + th));
            }
            *(h4*)(Gb + (size_t)n * Cc + c0) = gv;
        }
    }
}

// ---------------------------------------------------------------------------
// MFMA GEMM (f16 in, fp32 acc), 128xBN tile, BK=32, ring-of-3 LDS buffers,
// counted vmcnt + raw s_barrier (r3 structure, verified). EPI 1/3/4.
// EPI1 writes v into BLOCKED layout VB[b][c/16][m/32][16][32].
// ---------------------------------------------------------------------------
template<int EPI, int BN, int SWZ>
__global__ __launch_bounds__(256) void gemm_mfma(
    const _Float16* __restrict__ Ah, long sA, int lda,
    const _Float16* __restrict__ Bh, long sB, int ldb,
    const float* __restrict__ aux, long sAux, int ldaux,     // f32 bias
    void* __restrict__ Cout, long sC, int ldc, int K, int GX)
{
    constexpr int NI  = (BN == 128) ? 4 : 2;
    constexpr int ASL = 512;
    constexpr int BSL = BN * 4;
    constexpr int NQ  = (ASL + BSL) / 256;

    __shared__ _Float16 As[3][128 * 32];
    __shared__ _Float16 Bs[3][BN * 32];

    int bx, by, bz;
    if (SWZ == 1) {
        const int id = blockIdx.x;
        bz = id & 7; bx = (id >> 3) % GX; by = (id >> 3) / GX;
    } else if (SWZ == 2) {
        const int id = blockIdx.x;
        bz = 0; bx = (id >> 3) % GX; by = (id & 7) + 8 * ((id >> 3) / GX);
    } else {
        bx = blockIdx.x; by = blockIdx.y; bz = 0;
    }

    const _Float16* A0 = Ah + (size_t)bz * sA;
    const _Float16* B0 = Bh + (size_t)bz * sB;

    const int tid  = threadIdx.x;
    const int wv   = tid >> 6;
    const int ln   = tid & 63;
    const int wx   = (BN == 128) ? (wv & 1) : 0;
    const int wy   = (BN == 128) ? (wv >> 1) : wv;
    const int lcol = ln & 15, quad = ln >> 4;
    const int row0w = wy * (NI * 16);
    const int col0w = wx * 64;

    const int rowBase = by * 128;
    const int colBase = bx * BN;
    const int soff = (quad ^ ((lcol >> 1) & 3)) * 8;

    f4 acc[NI][4];
    const f4 z4 = {0.f, 0.f, 0.f, 0.f};
    #pragma unroll
    for (int i = 0; i < NI; ++i)
        #pragma unroll
        for (int j = 0; j < 4; ++j) acc[i][j] = z4;

    auto STAGE = [&](int k0, int p) {
        #pragma unroll
        for (int q = 0; q < NQ; ++q) {
            const int c = q * 256 + wv * 64 + ln;
            if (c < ASL) {
                const int r = c >> 2;
                const int g = (c & 3) ^ ((c >> 3) & 3);
                gld16(A0 + (size_t)(rowBase + r) * lda + k0 + g * 8, &As[p][c * 8]);
            } else {
                const int cb = c - ASL;
                const int r  = cb >> 2;
                const int g  = (cb & 3) ^ ((cb >> 3) & 3);
                gld16(B0 + (size_t)(colBase + r) * ldb + k0 + g * 8, &Bs[p][cb * 8]);
            }
        }
    };

    const int NT = K >> 5;
    STAGE(0, 0);
    STAGE(32, 1);
    wait_vmcnt<NQ>();
    __builtin_amdgcn_s_barrier();

    int p = 0, pn2 = 2;
    for (int t = 0; t < NT; ++t) {
        if (t + 2 < NT) STAGE((t + 2) * 32, pn2);

        hfrag af[NI], bf_[4];
        #pragma unroll
        for (int i = 0; i < NI; ++i)
            af[i]  = *(const hfrag*)&As[p][(row0w + i * 16 + lcol) * 32 + soff];
        #pragma unroll
        for (int j = 0; j < 4; ++j)
            bf_[j] = *(const hfrag*)&Bs[p][(col0w + j * 16 + lcol) * 32 + soff];

        #pragma unroll
        for (int i = 0; i < NI; ++i)
            #pragma unroll
            for (int j = 0; j < 4; ++j)
                acc[i][j] = __builtin_amdgcn_mfma_f32_16x16x32_f16(af[i], bf_[j], acc[i][j], 0, 0, 0);

        if (t + 1 < NT) {
            if (t + 2 < NT) wait_vmcnt<NQ>();
            else            wait_vmcnt<0>();
            __builtin_amdgcn_s_barrier();
        }
        p   = (p   == 2) ? 0 : p + 1;
        pn2 = (pn2 == 2) ? 0 : pn2 + 1;
    }

    const int crow0 = rowBase + row0w + quad * 4;
    const int ccol0 = colBase + col0w + lcol;

    if (EPI == 1) {            // v blocked: VB[b][c/16][m/32][16][32]
        _Float16* C = (_Float16*)Cout;
        #pragma unroll
        for (int j = 0; j < 4; ++j) {
            const int col = ccol0 + j * 16;          // c index
            const float bi = aux[col];
            #pragma unroll
            for (int i = 0; i < NI; ++i) {
                const int rowb = crow0 + i * 16;     // flattened b*M + m
                const int bb = rowb >> 11, ml = rowb & 2047;
                h4 st;
                #pragma unroll
                for (int r = 0; r < 4; ++r) st[r] = (_Float16)(acc[i][j][r] + bi);
                *(h4*)(C + (size_t)bb * 1048576 +
                       ((col >> 4) * 32768 + (ml >> 5) * 512 +
                        (col & 15) * 32 + (ml & 31))) = st;
            }
        }
    } else if (EPI == 3) {     // fc1: h[n][c2] = relu(acc + b1[c2]), h4
        _Float16* C = (_Float16*)Cout;
        #pragma unroll
        for (int i = 0; i < NI; ++i) {
            const int c0 = crow0 + i * 16;
            const f4 bi = *(const f4*)(aux + c0);
            #pragma unroll
            for (int j = 0; j < 4; ++j) {
                const int n = ccol0 + j * 16;
                h4 hv;
                #pragma unroll
                for (int r = 0; r < 4; ++r)
                    hv[r] = (_Float16)fmaxf(acc[i][j][r] + bi[r], 0.f);
                *(h4*)(C + (size_t)n * ldc + c0) = hv;
            }
        }
    } else {                   // fc2: out[n][c3] = acc + b2[c3], f4 stores
        float* C = (float*)Cout;
        #pragma unroll
        for (int i = 0; i < NI; ++i) {
            const int c0 = crow0 + i * 16;
            const f4 bi = *(const f4*)(aux + c0);
            #pragma unroll
            for (int j = 0; j < 4; ++j) {
                const int n = ccol0 + j * 16;
                f4 ov;
                #pragma unroll
                for (int r = 0; r < 4; ++r) ov[r] = acc[i][j][r] + bi[r];
                *(f4*)(C + (size_t)n * ldc + c0) = ov;
            }
        }
    }
}

// W [512,512] fp32 -> Wt [512,512] f16 transposed (Wt[n][k] = W[k][n]).
__global__ __launch_bounds__(256) void wconv(const float* s0, const float* s1, const float* s2,
                                             _Float16* d0, _Float16* d1, _Float16* d2)
{
    const float* Sm = blockIdx.z == 0 ? s0 : blockIdx.z == 1 ? s1 : s2;
    _Float16* D = blockIdx.z == 0 ? d0 : blockIdx.z == 1 ? d1 : d2;
    __shared__ float t[32][33];
    const int x = threadIdx.x & 31, y = threadIdx.x >> 5;
    const int gx = blockIdx.x * 32, gy = blockIdx.y * 32;
    #pragma unroll
    for (int yy = y; yy < 32; yy += 8)
        t[yy][x] = Sm[(size_t)(gy + yy) * 512 + gx + x];
    __syncthreads();
    #pragma unroll
    for (int yy = y; yy < 32; yy += 8)
        D[(size_t)(gx + yy) * 512 + gy + x] = (_Float16)t[x][yy];
}

// ---------------------------------------------------------------------------
// ws layout (all within proven 142MB envelope):
//   EB   [0x0000000, 0x1000000)  enc blocked f16
//   DB   [0x1000000, 0x2000000)  dec blocked f16
//   VB   [0x2000000, 0x3000000)  v blocked f16
//   Wvt/W1t/W2t [0x5600000, +3*512KB)
//   g    [0x6800000, 0x7800000)  f16 [bn][c]
//   h    [0x7800000, 0x8800000)  f16 [bn][c2]
//   enc_h linear in d_out (dead before fc2 writes).
// ---------------------------------------------------------------------------
extern "C" void kernel_launch(void* const* d_in, const int* in_sizes, int n_in,
                              void* d_out, int out_size, void* d_ws, size_t ws_size,
                              hipStream_t stream)
{
    const float* dec   = (const float*)d_in[0];
    const float* enc   = (const float*)d_in[1];
    const float* trans = (const float*)d_in[2];
    const float* Wv = (const float*)d_in[3];
    const float* bv = (const float*)d_in[4];
    const float* W1 = (const float*)d_in[5];
    const float* b1 = (const float*)d_in[6];
    const float* W2 = (const float*)d_in[7];
    const float* b2 = (const float*)d_in[8];

    char* ws = (char*)d_ws;
    _Float16* EBw   = (_Float16*)ws;
    _Float16* DBw   = (_Float16*)(ws + 0x1000000);
    _Float16* VBw   = (_Float16*)(ws + 0x2000000);
    _Float16* Wvt   = (_Float16*)(ws + 0x5600000);
    _Float16* W1t   = Wvt + 262144;
    _Float16* W2t   = Wvt + 524288;
    _Float16* g     = (_Float16*)(ws + 0x6800000);
    _Float16* h     = (_Float16*)(ws + 0x7800000);
    _Float16* enc_h = (_Float16*)d_out;

    sconv2<<<dim3(8192), 256, 0, stream>>>(dec, nullptr, DBw);
    sconv2<<<dim3(8192), 256, 0, stream>>>(enc, enc_h, EBw);
    wconv<<<dim3(16, 16, 3), 256, 0, stream>>>(Wv, W1, W2, Wvt, W1t, W2t);

    // v = (enc @ Wv + bv), written fragment-blocked  [SWZ2, GX=8]
    gemm_mfma<1, 64, 2><<<dim3(1024), 256, 0, stream>>>(
        enc_h, 0, 512, Wvt, 0, 512, bv, 0, 0,
        VBw, 0, 0, 512, 8);

    // fused: score + masked-softmax + PV + gate -> g  (blocked operands)
    attn_fused<<<dim3(512), 256, 0, stream>>>(EBw, DBw, VBw, trans, g);

    // h[n][c2] = relu(g @ W1 + b1):  A=W1^T (rows=c2), B=g (cols=n)
    gemm_mfma<3, 64, 0><<<dim3(256, 4), 256, 0, stream>>>(
        W1t, 0, 512, g, 0, 512, b1, 0, 0,
        h, 0, 512, 512, 0);

    // out[n][c3] = h @ W2 + b2:  A=W2^T (rows=c3), B=h (cols=n), fp32
    gemm_mfma<4, 64, 0><<<dim3(256, 4), 256, 0, stream>>>(
        W2t, 0, 512, h, 0, 512, b2, 0, 0,
        d_out, 0, 512, 512, 0);
}